// Round 18
// baseline (349.380 us; speedup 1.0000x reference)
//
#include <hip/hip_runtime.h>
#include <stdint.h>

// ---------------- constants ----------------
constexpr int H = 1024, W = 1024;
constexpr int NPIX = H * W;            // 1048576
constexpr int PADM = 24;               // max pad (ws=49)
constexpr int PROW = W + 2 * PADM;     // 1072 padded row length

// workspace layout (bytes)
constexpr size_t OFF_F2P   = 134217728;                 // f2 NHWC 16c packed u32 = 64MB
// region [0,128MB): f3 + box buffers
constexpr size_t OFF_F3    = 0;                         // f3 NCHW 8c fp32 = 32MB
constexpr size_t OFF_HF    = 33554432;                  // 32MB (scale A)
constexpr size_t OFF_HF2   = 67108864;                  // 32MB
constexpr size_t OFF_FUSED = 100663296;                 // 4MB
// after conv3, f2p region is dead -> scale-B hf pair lives there:
constexpr size_t OFF_HF25  = 134217728;                 // 32MB
constexpr size_t OFF_HF225 = 167772160;                 // 32MB (ends exactly at 201326592)
// small region past 192MB
constexpr size_t OFF_SMALL  = 201326592;
constexpr size_t OFF_PSTAT  = OFF_SMALL;            // 256*2 doubles = 4096B
constexpr size_t OFF_NMSUM  = OFF_SMALL + 4096;     // 1 double (pad 64)
constexpr size_t OFF_HIST   = OFF_SMALL + 4160;     // 8*256 u32 = 8KB
constexpr size_t OFF_RSTATE = OFF_HIST + 8192;      // 16 u32 (pad 64)
constexpr size_t OFF_SCAL   = OFF_RSTATE + 64;      // 2 floats (pad 64)
constexpr size_t OFF_H0     = OFF_SCAL + 64;        // 256 u32 = 1KB (pass-0 hist)
constexpr size_t OFF_WT     = OFF_H0 + 1024;        // bf16 weight frags (~36KB)

using short8  = __attribute__((ext_vector_type(8))) short;
using short4v = __attribute__((ext_vector_type(4))) short;
using f32x4   = __attribute__((ext_vector_type(4))) float;
using uint2v  = __attribute__((ext_vector_type(2))) unsigned int;
using uint4v  = __attribute__((ext_vector_type(4))) unsigned int;

__device__ __forceinline__ int reflect1024(int j) {
    return j < 0 ? -j : (j > 1023 ? 2046 - j : j);
}
__device__ __forceinline__ unsigned short rne_bf16(float v) {
    uint32_t u = __float_as_uint(v);
    return (unsigned short)((u + 0x7FFFu + ((u >> 16) & 1u)) >> 16);
}
__device__ __forceinline__ float bf16f(unsigned short h) {
    return __uint_as_float(((uint32_t)h) << 16);
}
__device__ __forceinline__ uint32_t pack_hl(float v) {
    uint32_t u = __float_as_uint(v);
    unsigned short hh = (unsigned short)(u >> 16);
    unsigned short ll = rne_bf16(v - __uint_as_float(u & 0xFFFF0000u));
    return (uint32_t)hh | ((uint32_t)ll << 16);
}

// ---------------- prep kernel: init + 3x wfrag + x-stats partials ----------------
__device__ void wfrag_body(const float* __restrict__ w, unsigned short* __restrict__ wfH,
                           unsigned short* __restrict__ wfL, int CIN, int COUT, int NF, int S,
                           int blk) {
    int total = NF * S * 512;
    int e = blk * 256 + threadIdx.x;
    if (e >= total) return;
    int j = e & 7, l = (e >> 3) & 63;
    int rest = e >> 9;
    int s = rest % S, nf = rest / S;
    int k = s * 32 + ((l >> 4) << 3) + j;
    int n = (l & 15) + 16 * nf;
    float v = 0.f;
    if (k < 9 * CIN && n < COUT) {
        int kk = k / CIN, c = k % CIN;
        int ky = kk / 3, kx = kk - ky * 3;
        v = w[((n * CIN + c) * 3 + ky) * 3 + kx];
    }
    unsigned short h = rne_bf16(v);
    wfH[e] = h;
    wfL[e] = rne_bf16(v - bf16f(h));
}

__global__ void prep_kernel(const float* __restrict__ w1, const float* __restrict__ w2,
                            const float* __restrict__ w3,
                            unsigned short* wf1H, unsigned short* wf1L,
                            unsigned short* wf2H, unsigned short* wf2L,
                            unsigned short* wf3H, unsigned short* wf3L,
                            const float* __restrict__ x, double* __restrict__ pstats,
                            double* nmsum, uint32_t* hist, uint32_t* rstate,
                            uint32_t* h0) {
    __shared__ double sb1[256], sb2[256];
    const int b = blockIdx.x, tid = threadIdx.x;
    if (b == 0) {
        for (int i = tid; i < 2048; i += 256) hist[i] = 0u;
        h0[tid] = 0u;
        if (tid == 0) nmsum[0] = 0.0;
        if (tid < 8) rstate[tid] = 0u;
        if (tid < 8) {
            const uint32_t ranks[8] = {262143u, 262144u, 314572u, 314573u,
                                       734002u, 734003u, 786431u, 786432u};
            rstate[8 + tid] = ranks[tid];
        }
    } else if (b < 9) {
        wfrag_body(w1, wf1H, wf1L, 4, 32, 2, 2, b - 1);
    } else if (b < 27) {
        wfrag_body(w2, wf2H, wf2L, 32, 16, 1, 9, b - 9);
    } else if (b < 37) {
        wfrag_body(w3, wf3H, wf3L, 16, 8, 1, 5, b - 27);
    } else {
        int sb = b - 37;                 // 0..255
        int ch = sb >> 6, blk = sb & 63;
        const float* p = x + (size_t)ch * NPIX;
        double s1 = 0.0, s2 = 0.0;
        for (int i = blk * 256 + tid; i < NPIX; i += 64 * 256) {
            double v = (double)p[i];
            s1 += v; s2 += v * v;
        }
        sb1[tid] = s1; sb2[tid] = s2;
        __syncthreads();
        for (int off = 128; off > 0; off >>= 1) {
            if (tid < off) { sb1[tid] += sb1[tid + off]; sb2[tid] += sb2[tid + off]; }
            __syncthreads();
        }
        if (tid == 0) { pstats[sb * 2] = sb1[0]; pstats[sb * 2 + 1] = sb2[0]; }
    }
}

// ---------------- FUSED conv1+conv2 (bf16x3, MFMA implicit-GEMM) ----------------
// Block 256 = 4 waves; output tile 64x4 of f2 (NHWC packed u32).
// Stage x halo 8x68x4 -> bf16 h/l; compute f1 tile 6x66x32 in-block (25 M-tiles of
// 16 over m = fr*66+fp) into Ah/Al LDS (zeroing f1 outside the image, matching the
// old zero-pad staging); then run the proven conv2 K-loop + packed epilogue.
__global__ __launch_bounds__(256, 2) void mconv12_kernel(
        const float* __restrict__ x,
        const unsigned short* __restrict__ wf1H, const unsigned short* __restrict__ wf1L,
        const float* __restrict__ b1,
        const unsigned short* __restrict__ wf2H, const unsigned short* __restrict__ wf2L,
        const float* __restrict__ b2, uint32_t* __restrict__ out) {
    constexpr int XRS = 68 * 4;          // 272
    constexpr int RS  = 66 * 32;         // 2112
    constexpr int PSTR = 16 + 4;         // padded px stride (u32) for epilogue
    __shared__ __align__(16) unsigned short Xh[8 * XRS], Xl[8 * XRS];
    __shared__ __align__(16) unsigned short Ah[6 * RS], Al[6 * RS];

    const int tid = threadIdx.x;
    const int bx = blockIdx.x * 64, by = blockIdx.y * 4;
    const int lane = tid & 63, rw = tid >> 6;
    const int nidx = lane & 15;
    const int mrow = (lane >> 4) * 4;

    // ---- stage x halo: 8 rows x 68 px x 4 ch ----
    {
        constexpr int TOT = 8 * 4 * 68;          // 2176
        constexpr int NLOAD = (TOT + 255) / 256; // 9
        float regs[NLOAD];
#pragma unroll
        for (int k = 0; k < NLOAD; ++k) {
            int idx = tid + k * 256;
            float v = 0.f;
            if (idx < TOT) {
                int rc = idx / 68, sp = idx - rc * 68;
                int r = rc >> 2, c = rc & 3;
                int gy = by - 2 + r, gx = bx - 2 + sp;
                if ((unsigned)gy < 1024u && (unsigned)gx < 1024u)
                    v = x[(size_t)c * NPIX + ((size_t)gy << 10) + gx];
            }
            regs[k] = v;
        }
#pragma unroll
        for (int k = 0; k < NLOAD; ++k) {
            int idx = tid + k * 256;
            if (idx < TOT) {
                int rc = idx / 68, sp = idx - rc * 68;
                int r = rc >> 2, c = rc & 3;
                uint32_t u = __float_as_uint(regs[k]);
                Xh[r * XRS + sp * 4 + c] = (unsigned short)(u >> 16);
                Xl[r * XRS + sp * 4 + c] =
                    rne_bf16(regs[k] - __uint_as_float(u & 0xFFFF0000u));
            }
        }
    }

    // ---- weight frags -> VGPRs ----
    short8 w1h[2][2], w1l[2][2];
#pragma unroll
    for (int nf = 0; nf < 2; ++nf)
#pragma unroll
        for (int s = 0; s < 2; ++s) {
            w1h[nf][s] = *(const short8*)(wf1H + (size_t)((nf * 2 + s) * 64 + lane) * 8);
            w1l[nf][s] = *(const short8*)(wf1L + (size_t)((nf * 2 + s) * 64 + lane) * 8);
        }
    short8 w2h[9], w2l[9];
#pragma unroll
    for (int s = 0; s < 9; ++s) {
        w2h[s] = *(const short8*)(wf2H + (size_t)(s * 64 + lane) * 8);
        w2l[s] = *(const short8*)(wf2L + (size_t)(s * 64 + lane) * 8);
    }
    const float b1v0 = b1[nidx], b1v1 = b1[nidx + 16];
    const float b2v = b2[nidx];

    __syncthreads();

    // ---- compute f1 tile: 25 M-tiles of 16 over m = fr*66 + fp ----
    const int g2 = (lane >> 4) * 2;
#pragma unroll 1
    for (int tt = 0; tt < 7; ++tt) {
        int mt = rw + 4 * tt;
        if (mt >= 25) break;
        int m = mt * 16 + nidx;
        int mm = (m < 396) ? m : 0;
        int fr = mm / 66, fp = mm - fr * 66;
        f32x4 a1[2];
        a1[0] = f32x4{b1v0, b1v0, b1v0, b1v0};
        a1[1] = f32x4{b1v1, b1v1, b1v1, b1v1};
#pragma unroll
        for (int s = 0; s < 2; ++s) {
            int kkA = s * 8 + g2, kkB = kkA + 1;
            int poA = (kkA <= 8) ? ((fr + kkA / 3) * XRS + (fp + kkA % 3) * 4)
                                 : (fr * XRS + fp * 4);
            int poB = (kkB <= 8) ? ((fr + kkB / 3) * XRS + (fp + kkB % 3) * 4)
                                 : (fr * XRS + fp * 4);
            union { short4v q[2]; short8 o; } ua, ub;
            ua.q[0] = *(const short4v*)(Xh + poA);
            ua.q[1] = *(const short4v*)(Xh + poB);
            ub.q[0] = *(const short4v*)(Xl + poA);
            ub.q[1] = *(const short4v*)(Xl + poB);
            short8 a = ua.o, b = ub.o;
#pragma unroll
            for (int nf = 0; nf < 2; ++nf) {
                a1[nf] = __builtin_amdgcn_mfma_f32_16x16x32_bf16(a, w1h[nf][s], a1[nf], 0, 0, 0);
                a1[nf] = __builtin_amdgcn_mfma_f32_16x16x32_bf16(b, w1h[nf][s], a1[nf], 0, 0, 0);
                a1[nf] = __builtin_amdgcn_mfma_f32_16x16x32_bf16(a, w1l[nf][s], a1[nf], 0, 0, 0);
            }
        }
        // write f1 (leaky) -> Ah/Al; zero outside image (matches old zero-pad staging)
#pragma unroll
        for (int j = 0; j < 4; ++j) {
            int mo = mt * 16 + mrow + j;
            if (mo < 396) {
                int ofr = mo / 66, ofp = mo - ofr * 66;
                int ay = by - 1 + ofr, ax = bx - 1 + ofp;
                bool inimg = ((unsigned)ay < 1024u) && ((unsigned)ax < 1024u);
#pragma unroll
                for (int nf = 0; nf < 2; ++nf) {
                    float v = a1[nf][j];
                    v = v >= 0.f ? v : 0.2f * v;
                    if (!inimg) v = 0.f;
                    uint32_t u = __float_as_uint(v);
                    unsigned short hh = (unsigned short)(u >> 16);
                    int off = ofr * RS + ofp * 32 + nf * 16 + nidx;
                    Ah[off] = hh;
                    Al[off] = rne_bf16(v - __uint_as_float(u & 0xFFFF0000u));
                }
            }
        }
    }

    // ---- conv2 accumulators ----
    f32x4 acc[4];
#pragma unroll
    for (int t = 0; t < 4; ++t) acc[t] = f32x4{b2v, b2v, b2v, b2v};

    __syncthreads();

    // ---- conv2 K loop (CIN=32, S=9, NF=1) ----
    {
        const int base = rw * RS + nidx * 32 + (lane >> 4) * 8;
        const unsigned short* pah = Ah + base;
        const unsigned short* pal = Al + base;
#pragma unroll
        for (int s = 0; s < 9; ++s) {
            const int ky = s / 3, kx = s - (s / 3) * 3;
#pragma unroll
            for (int t = 0; t < 4; ++t) {
                const int off = ky * RS + kx * 32 + t * 512;
                short8 a = *(const short8*)(pah + off);
                short8 b = *(const short8*)(pal + off);
                acc[t] = __builtin_amdgcn_mfma_f32_16x16x32_bf16(a, w2h[s], acc[t], 0, 0, 0);
                acc[t] = __builtin_amdgcn_mfma_f32_16x16x32_bf16(b, w2h[s], acc[t], 0, 0, 0);
                acc[t] = __builtin_amdgcn_mfma_f32_16x16x32_bf16(a, w2l[s], acc[t], 0, 0, 0);
            }
        }
    }

    // ---- epilogue: f2 (COUT=16, leaky) packed u32 NHWC, coalesced stores ----
    __syncthreads();
    uint32_t* pk = (uint32_t*)Ah;          // [4 rows][64 px][PSTR] = 20480B < Ah
#pragma unroll
    for (int t = 0; t < 4; ++t)
#pragma unroll
        for (int j = 0; j < 4; ++j) {
            float v = acc[t][j];
            v = v >= 0.f ? v : 0.2f * v;
            int xl = t * 16 + mrow + j;
            pk[(rw * 64 + xl) * PSTR + nidx] = pack_hl(v);
        }
    __syncthreads();
    {
        constexpr int ROWU = 64 * 16;      // 1024 u32 per row-tile
        constexpr int NU4 = 4 * ROWU / 4;  // 1024 uint4 chunks
#pragma unroll
        for (int k = 0; k < NU4 / 256; ++k) {
            int i = tid + k * 256;
            int e = i * 4;
            int r = e / ROWU;
            int rem = e - r * ROWU;
            int px = rem / 16, c = rem - px * 16;
            uint4v val = *(const uint4v*)&pk[(r * 64 + px) * PSTR + c];
            *(uint4v*)(out + ((size_t)(((by + r) << 10) + bx + px)) * 16 + c) = val;
        }
    }
}

// ---------------- conv3: MFMA implicit-GEMM (CIN=16 -> COUT=8, NCHW fp32 out) -------
template <int CIN, int COUT, int S, bool LEAKY, int MINW>
__global__ __launch_bounds__(256, MINW) void mconv_kernel(
        const void* __restrict__ in,
        const unsigned short* __restrict__ wfH, const unsigned short* __restrict__ wfL,
        const float* __restrict__ bias, void* __restrict__ out) {
    constexpr int NF = (COUT + 15) / 16;
    constexpr int RS = 66 * CIN;                       // LDS row stride (bf16 elems)
    constexpr int STAGEB = 2 * (6 * RS) * 2;           // Ah+Al bytes
    constexpr int EPIB = COUT * 4 * 66 * 4;
    constexpr int LBYTES = STAGEB > EPIB ? STAGEB : EPIB;
    __shared__ __align__(16) unsigned char LB[LBYTES];
    unsigned short* Ah = (unsigned short*)LB;
    unsigned short* Al = Ah + 6 * RS;

    const int tid = threadIdx.x;
    const int bx = blockIdx.x * 64, by = blockIdx.y * 4;
    const int lane = tid & 63, rw = tid >> 6;

    {
        constexpr int CPP = CIN / 4;
        constexpr int CROW = 66 * CPP;
        constexpr int TOT = 6 * CROW;
        constexpr int NLOAD = (TOT + 255) / 256;
        const uint32_t* gp = (const uint32_t*)in;

        uint4v regs[NLOAD];
#pragma unroll
        for (int k = 0; k < NLOAD; ++k) {
            int idx = tid + k * 256;
            uint4v v = uint4v{0u, 0u, 0u, 0u};
            if (idx < TOT) {
                int r = idx / CROW;
                int j = idx - r * CROW;
                int gy = by - 1 + r;
                int gx = bx - 1 + j / CPP;
                if ((unsigned)gy < 1024u && (unsigned)gx < 1024u)
                    v = *(const uint4v*)(gp + ((size_t)gy << 10) * CIN +
                                         (size_t)(bx - 1) * CIN + (size_t)j * 4);
            }
            regs[k] = v;
        }
#pragma unroll
        for (int k = 0; k < NLOAD; ++k) {
            int idx = tid + k * 256;
            if (idx < TOT) {
                int r = idx / CROW;
                int j = idx - r * CROW;
                int px = j / CPP, c0 = (j - px * CPP) * 4;
                uint32_t p0 = regs[k].x, p1 = regs[k].y, p2 = regs[k].z, p3 = regs[k].w;
                uint2v hh, ll;
                hh.x = __builtin_amdgcn_perm(p1, p0, 0x05040100u);
                hh.y = __builtin_amdgcn_perm(p3, p2, 0x05040100u);
                ll.x = __builtin_amdgcn_perm(p1, p0, 0x07060302u);
                ll.y = __builtin_amdgcn_perm(p3, p2, 0x07060302u);
                int off = r * RS + px * CIN + c0;
                *(uint2v*)(Ah + off) = hh;
                *(uint2v*)(Al + off) = ll;
            }
        }
    }

    short8 wh[NF][S], wl[NF][S];
#pragma unroll
    for (int nf = 0; nf < NF; ++nf)
#pragma unroll
        for (int s = 0; s < S; ++s) {
            wh[nf][s] = *(const short8*)(wfH + (size_t)((nf * S + s) * 64 + lane) * 8);
            wl[nf][s] = *(const short8*)(wfL + (size_t)((nf * S + s) * 64 + lane) * 8);
        }

    const int nidx = lane & 15;
    f32x4 acc[4][NF];
#pragma unroll
    for (int nf = 0; nf < NF; ++nf) {
        float bv = (nidx + nf * 16 < COUT) ? bias[nidx + nf * 16] : 0.f;
#pragma unroll
        for (int t = 0; t < 4; ++t) acc[t][nf] = f32x4{bv, bv, bv, bv};
    }

    __syncthreads();

    {
        const int g23 = lane >> 5;
        const int base = rw * RS + (lane & 15) * 16 + ((lane >> 4) & 1) * 8;
#pragma unroll
        for (int s = 0; s < S; ++s) {
            const int kk0 = 2 * s, kk1 = 2 * s + 1;
            const int O0 = (kk0 / 3) * RS + (kk0 - (kk0 / 3) * 3) * 16;
            const int O1 = (kk1 <= 8) ? (kk1 / 3) * RS + (kk1 - (kk1 / 3) * 3) * 16 : 0;
            const int offs = base + (g23 ? O1 : O0);
#pragma unroll
            for (int t = 0; t < 4; ++t) {
                short8 a = *(const short8*)(Ah + offs + t * 256);
                short8 b = *(const short8*)(Al + offs + t * 256);
#pragma unroll
                for (int nf = 0; nf < NF; ++nf) {
                    acc[t][nf] = __builtin_amdgcn_mfma_f32_16x16x32_bf16(a, wh[nf][s], acc[t][nf], 0, 0, 0);
                    acc[t][nf] = __builtin_amdgcn_mfma_f32_16x16x32_bf16(b, wh[nf][s], acc[t][nf], 0, 0, 0);
                    acc[t][nf] = __builtin_amdgcn_mfma_f32_16x16x32_bf16(a, wl[nf][s], acc[t][nf], 0, 0, 0);
                }
            }
        }
    }

    const int mrow = (lane >> 4) * 4;
    __syncthreads();
    float* smem = (float*)LB;              // [COUT][4][66]
    if (nidx < COUT) {
#pragma unroll
        for (int t = 0; t < 4; ++t)
#pragma unroll
            for (int j = 0; j < 4; ++j) {
                float v = acc[t][0][j];
                if (LEAKY) v = v >= 0.f ? v : 0.2f * v;
                smem[(nidx * 4 + rw) * 66 + t * 16 + mrow + j] = v;
            }
    }
    __syncthreads();
    float* outp = (float*)out;
#pragma unroll
    for (int k = 0; k < COUT; ++k) {
        int i = tid + k * 256;
        int px = i & 63, r = (i >> 6) & 3, c = i >> 8;
        outp[(size_t)c * NPIX + ((size_t)(by + r) << 10) + bx + px] =
            smem[(c * 4 + r) * 66 + px];
    }
}

// ---------------- horizontal box sums via row prefix-sum (reflect pad) --------------
template <bool DOB>
__global__ void hbox_kernel(const float* __restrict__ f3,
                            float* __restrict__ hfA, float* __restrict__ hf2A, int pA,
                            float* __restrict__ hfB, float* __restrict__ hf2B, int pB) {
    const int row = blockIdx.x, ch = blockIdx.y, tid = threadIdx.x;
    const float* src = f3 + ch * NPIX + row * W;
    __shared__ float sraw[PROW];
    __shared__ float Pf[PROW + 1], Pf2[PROW + 1];
    __shared__ float wtot[4], wtot2[4];

    for (int i = tid; i < PROW; i += 256)
        sraw[i] = src[reflect1024(i - PADM)];
    __syncthreads();

    float lf[5], lf2[5];
    float sf = 0.f, sf2 = 0.f;
    const int base = tid * 5;
#pragma unroll
    for (int j = 0; j < 5; ++j) {
        int idx = base + j;
        float v = (idx < PROW) ? sraw[idx] : 0.f;
        sf += v;      lf[j] = sf;
        sf2 += v * v; lf2[j] = sf2;
    }
    const int lane = tid & 63, wid = tid >> 6;
    float tf = sf, tf2 = sf2;
#pragma unroll
    for (int off = 1; off < 64; off <<= 1) {
        float a = __shfl_up(tf, off);
        float b = __shfl_up(tf2, off);
        if (lane >= off) { tf += a; tf2 += b; }
    }
    if (lane == 63) { wtot[wid] = tf; wtot2[wid] = tf2; }
    __syncthreads();
    float bse = 0.f, bse2 = 0.f;
    for (int w2 = 0; w2 < wid; ++w2) { bse += wtot[w2]; bse2 += wtot2[w2]; }
    float ex = bse + tf - sf, ex2 = bse2 + tf2 - sf2;
    if (base <= PROW) { Pf[base] = ex; Pf2[base] = ex2; }
#pragma unroll
    for (int j = 0; j < 5; ++j) {
        int idx = base + j + 1;
        if (idx <= PROW) { Pf[idx] = ex + lf[j]; Pf2[idx] = ex2 + lf2[j]; }
    }
    __syncthreads();

    float* dfA  = hfA  + ch * NPIX + row * W;
    float* df2A = hf2A + ch * NPIX + row * W;
    float* dfB  = DOB ? (hfB  + ch * NPIX + row * W) : nullptr;
    float* df2B = DOB ? (hf2B + ch * NPIX + row * W) : nullptr;
    for (int x = tid; x < W; x += 256) {
        int a = x + PADM - pA, b = x + PADM + pA + 1;
        dfA[x]  = Pf[b]  - Pf[a];
        df2A[x] = Pf2[b] - Pf2[a];
        if (DOB) {
            int a2 = x + PADM - pB, b2 = x + PADM + pB + 1;
            dfB[x]  = Pf[b2]  - Pf[a2];
            df2B[x] = Pf2[b2] - Pf2[a2];
        }
    }
}

// ---------------- vertical sliding window + fused 1x1 accumulate ----------------
template <int VRSP, bool DOH>
__global__ __launch_bounds__(512) void vbox_kernel(const float* __restrict__ hf,
                                                   const float* __restrict__ hf2,
                                                   float* __restrict__ fused,
                                                   const float* __restrict__ fw,
                                                   const float* __restrict__ fb,
                                                   uint32_t* __restrict__ h0,
                                                   int kidx, int p, float inv_area) {
    const int tid = threadIdx.x;
    const int colIdx = tid & 63, ch = tid >> 6;
    const int col = blockIdx.x * 64 + colIdx;
    const int r0 = blockIdx.y * VRSP;
    const float* pf  = hf  + ch * NPIX + col;
    const float* pf2 = hf2 + ch * NPIX + col;

    __shared__ float ssq[8][8][65];
    __shared__ uint32_t lh[8][256];
    if (DOH) {
        for (int i = tid; i < 2048; i += 512) ((uint32_t*)lh)[i] = 0u;
    }

    float S1 = 0.f, S2 = 0.f;
    for (int t = -p; t <= p; ++t) {
        int rr = reflect1024(r0 + t);
        S1 += pf[rr * W];
        S2 += pf2[rr * W];
    }

    const float w = fw[kidx];
    const float bias0 = fb[0];
    const int jj = tid >> 6, cc = tid & 63;
    const int sub = jj;

    for (int rb = r0; rb < r0 + VRSP; rb += 8) {
#pragma unroll
        for (int j = 0; j < 8; ++j) {
            int r = rb + j;
            float m1 = S1 * inv_area, m2 = S2 * inv_area;
            float var = fmaxf(m2 - m1 * m1, 1e-6f);
            ssq[ch][j][colIdx] = sqrtf(var);
            int radd = reflect1024(r + 1 + p), rsub = reflect1024(r - p);
            S1 += pf[radd * W] - pf[rsub * W];
            S2 += pf2[radd * W] - pf2[rsub * W];
        }
        __syncthreads();
        float a = 0.f;
#pragma unroll
        for (int c8 = 0; c8 < 8; ++c8) a += ssq[c8][jj][cc];
        float m = powf(a * 0.125f, 0.8f);
        float* fp = fused + ((size_t)(rb + jj) << 10) + blockIdx.x * 64 + cc;
        float outv;
        if (kidx == 0)      { outv = bias0 + w * m; *fp = outv; }
        else if (kidx == 1) { outv = *fp + w * m;   *fp = outv; }
        else                { outv = fmaxf(*fp + w * m, 0.f); *fp = outv; }
        if (DOH) {
            uint32_t u = __float_as_uint(outv);
            uint32_t key = (u & 0x80000000u) ? ~u : (u | 0x80000000u);
            atomicAdd(&lh[sub][key >> 24], 1u);
        }
        __syncthreads();
    }

    if (DOH) {
        __syncthreads();
        if (tid < 256) {
            uint32_t v = 0;
#pragma unroll
            for (int s = 0; s < 8; ++s) v += lh[s][tid];
            if (v) atomicAdd(&h0[tid], v);
        }
    }
}

// ---------------- radix select (8 ranks, 8 bits/pass) ----------------
__global__ void radix_hist_kernel(const float* __restrict__ fused, uint32_t* __restrict__ hist,
                                  const uint32_t* __restrict__ rstate, int pass) {
    __shared__ uint32_t h[8][256];
    int tid = threadIdx.x;
    for (int i = tid; i < 2048; i += 256) ((uint32_t*)h)[i] = 0u;
    __syncthreads();

    uint32_t pref[8];
#pragma unroll
    for (int r = 0; r < 8; ++r) pref[r] = rstate[r];
    uint32_t maskHi = 0xFFFFFFFFu << (32 - 8 * pass);
    int shift = 24 - 8 * pass;

    const uint4v* fp4 = (const uint4v*)fused;
    for (int i = blockIdx.x * blockDim.x + tid; i < NPIX / 4; i += gridDim.x * blockDim.x) {
        uint4v u4 = fp4[i];
#pragma unroll
        for (int e = 0; e < 4; ++e) {
            uint32_t u = (e == 0) ? u4.x : (e == 1) ? u4.y : (e == 2) ? u4.z : u4.w;
            uint32_t key = (u & 0x80000000u) ? ~u : (u | 0x80000000u);
            uint32_t bin = (key >> shift) & 0xFFu;
#pragma unroll
            for (int r = 0; r < 8; ++r) {
                if (((key ^ pref[r]) & maskHi) == 0u)
                    atomicAdd(&h[r][bin], 1u);
            }
        }
    }
    __syncthreads();
    for (int i = tid; i < 2048; i += 256) {
        uint32_t v = ((uint32_t*)h)[i];
        if (v) atomicAdd(&hist[i], v);
    }
}

__device__ __forceinline__ float key_to_float(uint32_t k) {
    uint32_t u = (k & 0x80000000u) ? (k & 0x7FFFFFFFu) : ~k;
    return __uint_as_float(u);
}

__global__ void radix_scan_kernel(uint32_t* __restrict__ hist, uint32_t* __restrict__ rstate,
                                  int pass, const uint32_t* __restrict__ h0,
                                  const double* __restrict__ pstats,
                                  const float* __restrict__ cw, float* __restrict__ scal) {
    int tid = threadIdx.x;
    int shift = 24 - 8 * pass;
    const int lane = tid & 63, wv = tid >> 6;
    __shared__ uint32_t wsum[4];
    __shared__ uint32_t fkey[8];
    for (int r = 0; r < 8; ++r) {
        uint32_t c = (pass == 0) ? h0[tid] : hist[r * 256 + tid];
        uint32_t sc = c;
#pragma unroll
        for (int off = 1; off < 64; off <<= 1) {
            uint32_t t = __shfl_up(sc, off);
            if (lane >= off) sc += t;
        }
        if (lane == 63) wsum[wv] = sc;
        __syncthreads();
        uint32_t base = 0;
        for (int w2 = 0; w2 < wv; ++w2) base += wsum[w2];
        uint32_t incl = base + sc, excl = incl - c;
        uint32_t lr = rstate[8 + r];
        if (lr >= excl && lr < incl) {
            uint32_t nk = rstate[r] | (((uint32_t)tid) << shift);
            rstate[r] = nk;
            rstate[8 + r] = lr - excl;
            if (pass == 3) fkey[r] = nk;
        }
        if (pass > 0) hist[r * 256 + tid] = 0u;
        __syncthreads();
    }

    if (pass == 3) {
        double s1 = pstats[2 * tid], s2 = pstats[2 * tid + 1];
#pragma unroll
        for (int off = 32; off > 0; off >>= 1) {
            s1 += __shfl_down(s1, off);
            s2 += __shfl_down(s2, off);
        }
        __shared__ double gs[4][2];
        if ((tid & 63) == 0) { gs[tid >> 6][0] = s1; gs[tid >> 6][1] = s2; }
        __syncthreads();
        if (tid == 0) {
            float v[8];
#pragma unroll
            for (int r = 0; r < 8; ++r) v[r] = key_to_float(fkey[r]);
            float q25 = v[0] + 0.75f * (v[1] - v[0]);
            float q30 = v[2] + 0.5f * (v[3] - v[2]);
            float q70 = v[4] + 0.5f * (v[5] - v[4]);
            float q75 = v[6] + 0.25f * (v[7] - v[6]);

            const double N = (double)NPIX;
            float gstd[4];
#pragma unroll
            for (int c = 0; c < 4; ++c) {
                double a1 = gs[c][0], a2 = gs[c][1];
                double var = (a2 - a1 * a1 / N) / (N - 1.0);
                gstd[c] = (float)sqrt(var > 0.0 ? var : 0.0);
            }
            float m = fmaxf(fmaxf(cw[0], cw[1]), fmaxf(cw[2], cw[3]));
            float e0 = expf(cw[0] - m), e1 = expf(cw[1] - m);
            float e2 = expf(cw[2] - m), e3 = expf(cw[3] - m);
            float se = e0 + e1 + e2 + e3;
            float cwn[4] = {e0 / se, e1 / se, e2 / se, e3 / se};

            float iqr75 = q75 - q25;
            float low0 = q25 - 0.5f * iqr75;
            float up0  = q75 + 0.5f * iqr75;
            float lsum = 0.f, usum = 0.f;
#pragma unroll
            for (int c = 0; c < 4; ++c) {
                float gf = fminf(fmaxf(gstd[c] * 5.f, 0.5f), 2.f);
                float cs = cwn[c] * gstd[c];
                float cf = fminf(fmaxf(cs * 2.f, 0.8f), 1.2f);
                lsum += low0 * gf * cf;
                usum += up0 * gf * cf;
            }
            float lmean = 0.25f * lsum, umean = 0.25f * usum;
            float l_t = 0.5f * lmean + 0.5f * q30;
            float u_t = 0.5f * umean + 0.5f * q70;
            float iqr = q70 - q30;
            if (iqr < 0.01f) { l_t -= iqr; u_t += iqr; }
            float diff = u_t - l_t;
            float mid0 = 0.5f * (l_t + u_t);
            if (diff < 0.02f) { l_t = mid0 - 0.01f; u_t = mid0 + 0.01f; }
            scal[0] = 0.5f * (l_t + u_t);
            scal[1] = u_t - l_t;
        }
    }
}

// ---------------- sigmoid mean (no store, float4) ----------------
__global__ void sigmoid_kernel(const float* __restrict__ fused, const float* __restrict__ scal,
                               double* __restrict__ nmsum) {
    float mid = scal[0], sc = scal[1];
    float inv = 4.0f / sc;
    float local = 0.f;
    const f32x4* fp4 = (const f32x4*)fused;
    for (int i = blockIdx.x * blockDim.x + threadIdx.x; i < NPIX / 4; i += gridDim.x * blockDim.x) {
        f32x4 v = fp4[i];
#pragma unroll
        for (int e = 0; e < 4; ++e) {
            float t = (v[e] - mid) * inv;
            local += 1.0f / (1.0f + expf(-t));
        }
    }
    __shared__ float red[256];
    red[threadIdx.x] = local;
    __syncthreads();
    for (int off = 128; off > 0; off >>= 1) {
        if (threadIdx.x < off) red[threadIdx.x] += red[threadIdx.x + off];
        __syncthreads();
    }
    if (threadIdx.x == 0) atomicAdd(nmsum, (double)red[0]);
}

// ---------------- final mask (recompute sigmoid; float4) ----------------
__global__ void final_kernel(const float* __restrict__ fused, const float* __restrict__ scal,
                             const double* __restrict__ nmsum, float* __restrict__ out) {
    float nm = (float)(nmsum[0] / (double)NPIX);
    float a, b;
    if (nm > 0.65f)      { a = 0.10f; b = 0.50f; }
    else if (nm < 0.35f) { a = 0.20f; b = 0.50f; }
    else                 { a = 0.15f; b = 0.55f; }
    float mid = scal[0], inv = 4.0f / scal[1];
    const f32x4* fp4 = (const f32x4*)fused;
    f32x4* op4 = (f32x4*)out;
    for (int i = blockIdx.x * blockDim.x + threadIdx.x; i < NPIX / 4; i += gridDim.x * blockDim.x) {
        f32x4 v = fp4[i];
        f32x4 r;
#pragma unroll
        for (int e = 0; e < 4; ++e) {
            float t = (v[e] - mid) * inv;
            float n = 1.0f / (1.0f + expf(-t));
            r[e] = a + b * n;
        }
        op4[i] = r;
    }
}

// ---------------- launch ----------------
extern "C" void kernel_launch(void* const* d_in, const int* in_sizes, int n_in,
                              void* d_out, int out_size, void* d_ws, size_t ws_size,
                              hipStream_t stream) {
    const float* x   = (const float*)d_in[0];
    const float* w1  = (const float*)d_in[1];
    const float* b1  = (const float*)d_in[2];
    const float* w2  = (const float*)d_in[3];
    const float* b2  = (const float*)d_in[4];
    const float* w3  = (const float*)d_in[5];
    const float* b3  = (const float*)d_in[6];
    const float* cw  = (const float*)d_in[7];
    const float* fw  = (const float*)d_in[8];
    const float* fb  = (const float*)d_in[9];

    char* ws = (char*)d_ws;
    uint32_t* f2p = (uint32_t*)(ws + OFF_F2P);
    float* f3    = (float*)(ws + OFF_F3);     // NCHW 8c fp32
    float* hf    = (float*)(ws + OFF_HF);     // scale-A pair
    float* hf2   = (float*)(ws + OFF_HF2);
    float* hf25  = (float*)(ws + OFF_HF25);   // scale-B pair (over dead f2p)
    float* hf225 = (float*)(ws + OFF_HF225);
    float* fused = (float*)(ws + OFF_FUSED);
    double* pstats = (double*)(ws + OFF_PSTAT);
    double* nmsum  = (double*)(ws + OFF_NMSUM);
    uint32_t* hist   = (uint32_t*)(ws + OFF_HIST);
    uint32_t* rstate = (uint32_t*)(ws + OFF_RSTATE);
    float* scal = (float*)(ws + OFF_SCAL);
    uint32_t* h0 = (uint32_t*)(ws + OFF_H0);
    unsigned short* wf1H = (unsigned short*)(ws + OFF_WT);            // 2048 elems
    unsigned short* wf1L = wf1H + 2048;
    unsigned short* wf2H = wf1L + 2048;                               // 4608 elems
    unsigned short* wf2L = wf2H + 4608;
    unsigned short* wf3H = wf2L + 4608;                               // 2560 elems
    unsigned short* wf3L = wf3H + 2560;

    // prep: init + weight frags + x-stats partials (293 blocks)
    prep_kernel<<<293, 256, 0, stream>>>(w1, w2, w3, wf1H, wf1L, wf2H, wf2L, wf3H, wf3L,
                                         x, pstats, nmsum, hist, rstate, h0);

    // fused conv1+conv2 (x -> f2 packed), then conv3 (f2 -> f3 NCHW fp32)
    dim3 cgrid(16, 256);
    mconv12_kernel<<<cgrid, 256, 0, stream>>>(x, wf1H, wf1L, b1, wf2H, wf2L, b2, f2p);
    mconv_kernel<16, 8, 5, false, 4><<<cgrid, 256, 0, stream>>>(
        f2p, wf3H, wf3L, b3, f3);

    // multi-scale std maps + fused 1x1 accumulate (k order 0,1,2 via stream order)
    hbox_kernel<true><<<dim3(H, 8), 256, 0, stream>>>(f3, hf, hf2, 5, hf25, hf225, 12);
    vbox_kernel<32, false><<<dim3(16, 32), 512, 0, stream>>>(hf, hf2, fused, fw, fb,
                                                             nullptr, 0, 5, 1.0f / 121.0f);
    hbox_kernel<false><<<dim3(H, 8), 256, 0, stream>>>(f3, hf, hf2, 24,
                                                       nullptr, nullptr, 0);
    vbox_kernel<32, false><<<dim3(16, 32), 512, 0, stream>>>(hf25, hf225, fused, fw, fb,
                                                             nullptr, 1, 12, 1.0f / 625.0f);
    vbox_kernel<64, true><<<dim3(16, 16), 512, 0, stream>>>(hf, hf2, fused, fw, fb,
                                                            h0, 2, 24, 1.0f / 2401.0f);

    // exact quantiles: pass 0 histogram came from vbox; 3 more hist+scan passes
    radix_scan_kernel<<<1, 256, 0, stream>>>(hist, rstate, 0, h0, pstats, cw, scal);
    for (int pass = 1; pass < 4; ++pass) {
        radix_hist_kernel<<<1024, 256, 0, stream>>>(fused, hist, rstate, pass);
        radix_scan_kernel<<<1, 256, 0, stream>>>(hist, rstate, pass, h0, pstats, cw, scal);
    }

    sigmoid_kernel<<<1024, 256, 0, stream>>>(fused, scal, nmsum);
    final_kernel<<<1024, 256, 0, stream>>>(fused, scal, nmsum, (float*)d_out);
}

// Round 19
// 345.279 us; speedup vs baseline: 1.0119x; 1.0119x over previous
//
#include <hip/hip_runtime.h>
#include <stdint.h>

// ---------------- constants ----------------
constexpr int H = 1024, W = 1024;
constexpr int NPIX = H * W;            // 1048576
constexpr int PADM = 24;               // max pad (ws=49)
constexpr int PROW = W + 2 * PADM;     // 1072 padded row length

// workspace layout (bytes)
constexpr size_t OFF_F1P   = 0;                         // f1 NHWC 32c packed u32 = 128MB
constexpr size_t OFF_F2P   = 134217728;                 // f2 NHWC 16c packed u32 = 64MB
// region [0,128MB) reused after conv3 (f1 dead):
constexpr size_t OFF_F3    = 0;                         // f3 NCHW 8c fp32 = 32MB
constexpr size_t OFF_HF    = 33554432;                  // 32MB (scale A)
constexpr size_t OFF_HF2   = 67108864;                  // 32MB
constexpr size_t OFF_FUSED = 100663296;                 // 4MB
// after conv3, f2p region is dead -> scale-B hf pair lives there:
constexpr size_t OFF_HF25  = 134217728;                 // 32MB
constexpr size_t OFF_HF225 = 167772160;                 // 32MB (ends exactly at 201326592)
// small region past 192MB
constexpr size_t OFF_SMALL  = 201326592;
constexpr size_t OFF_PSTAT  = OFF_SMALL;            // 256*2 doubles = 4096B
constexpr size_t OFF_NMSUM  = OFF_SMALL + 4096;     // 1 double (pad 64)
constexpr size_t OFF_HIST   = OFF_SMALL + 4160;     // 8*256 u32 = 8KB
constexpr size_t OFF_RSTATE = OFF_HIST + 8192;      // 16 u32 (pad 64)
constexpr size_t OFF_SCAL   = OFF_RSTATE + 64;      // 2 floats (pad 64)
constexpr size_t OFF_H0     = OFF_SCAL + 64;        // 256 u32 = 1KB (pass-0 hist)
constexpr size_t OFF_WT     = OFF_H0 + 1024;        // bf16 weight frags (~36KB)

using short8  = __attribute__((ext_vector_type(8))) short;
using short4v = __attribute__((ext_vector_type(4))) short;
using f32x4   = __attribute__((ext_vector_type(4))) float;
using uint2v  = __attribute__((ext_vector_type(2))) unsigned int;
using uint4v  = __attribute__((ext_vector_type(4))) unsigned int;

__device__ __forceinline__ int reflect1024(int j) {
    return j < 0 ? -j : (j > 1023 ? 2046 - j : j);
}
__device__ __forceinline__ unsigned short rne_bf16(float v) {
    uint32_t u = __float_as_uint(v);
    return (unsigned short)((u + 0x7FFFu + ((u >> 16) & 1u)) >> 16);
}
__device__ __forceinline__ float bf16f(unsigned short h) {
    return __uint_as_float(((uint32_t)h) << 16);
}
__device__ __forceinline__ uint32_t pack_hl(float v) {
    uint32_t u = __float_as_uint(v);
    unsigned short hh = (unsigned short)(u >> 16);
    unsigned short ll = rne_bf16(v - __uint_as_float(u & 0xFFFF0000u));
    return (uint32_t)hh | ((uint32_t)ll << 16);
}

// ---------------- prep kernel: init + 3x wfrag + x-stats partials ----------------
__device__ void wfrag_body(const float* __restrict__ w, unsigned short* __restrict__ wfH,
                           unsigned short* __restrict__ wfL, int CIN, int COUT, int NF, int S,
                           int blk) {
    int total = NF * S * 512;
    int e = blk * 256 + threadIdx.x;
    if (e >= total) return;
    int j = e & 7, l = (e >> 3) & 63;
    int rest = e >> 9;
    int s = rest % S, nf = rest / S;
    int k = s * 32 + ((l >> 4) << 3) + j;
    int n = (l & 15) + 16 * nf;
    float v = 0.f;
    if (k < 9 * CIN && n < COUT) {
        int kk = k / CIN, c = k % CIN;
        int ky = kk / 3, kx = kk - ky * 3;
        v = w[((n * CIN + c) * 3 + ky) * 3 + kx];
    }
    unsigned short h = rne_bf16(v);
    wfH[e] = h;
    wfL[e] = rne_bf16(v - bf16f(h));
}

__global__ void prep_kernel(const float* __restrict__ w1, const float* __restrict__ w2,
                            const float* __restrict__ w3,
                            unsigned short* wf1H, unsigned short* wf1L,
                            unsigned short* wf2H, unsigned short* wf2L,
                            unsigned short* wf3H, unsigned short* wf3L,
                            const float* __restrict__ x, double* __restrict__ pstats,
                            double* nmsum, uint32_t* hist, uint32_t* rstate,
                            uint32_t* h0) {
    __shared__ double sb1[256], sb2[256];
    const int b = blockIdx.x, tid = threadIdx.x;
    if (b == 0) {
        for (int i = tid; i < 2048; i += 256) hist[i] = 0u;
        h0[tid] = 0u;
        if (tid == 0) nmsum[0] = 0.0;
        if (tid < 8) rstate[tid] = 0u;
        if (tid < 8) {
            const uint32_t ranks[8] = {262143u, 262144u, 314572u, 314573u,
                                       734002u, 734003u, 786431u, 786432u};
            rstate[8 + tid] = ranks[tid];
        }
    } else if (b < 9) {
        wfrag_body(w1, wf1H, wf1L, 4, 32, 2, 2, b - 1);
    } else if (b < 27) {
        wfrag_body(w2, wf2H, wf2L, 32, 16, 1, 9, b - 9);
    } else if (b < 37) {
        wfrag_body(w3, wf3H, wf3L, 16, 8, 1, 5, b - 27);
    } else {
        int sb = b - 37;                 // 0..255
        int ch = sb >> 6, blk = sb & 63;
        const float* p = x + (size_t)ch * NPIX;
        double s1 = 0.0, s2 = 0.0;
        for (int i = blk * 256 + tid; i < NPIX; i += 64 * 256) {
            double v = (double)p[i];
            s1 += v; s2 += v * v;
        }
        sb1[tid] = s1; sb2[tid] = s2;
        __syncthreads();
        for (int off = 128; off > 0; off >>= 1) {
            if (tid < off) { sb1[tid] += sb1[tid + off]; sb2[tid] += sb2[tid + off]; }
            __syncthreads();
        }
        if (tid == 0) { pstats[sb * 2] = sb1[0]; pstats[sb * 2 + 1] = sb2[0]; }
    }
}

// ---------------- MFMA implicit-GEMM 3x3 conv (bf16x3 split precision) ----------------
template <int CIN, int COUT, int S, bool LEAKY, int OUT_MODE, int IN_MODE, int MINW>
__global__ __launch_bounds__(256, MINW) void mconv_kernel(
        const void* __restrict__ in,
        const unsigned short* __restrict__ wfH, const unsigned short* __restrict__ wfL,
        const float* __restrict__ bias, void* __restrict__ out) {
    constexpr int NF = (COUT + 15) / 16;
    constexpr int RS = 66 * CIN;                       // LDS row stride (bf16 elems)
    constexpr int PSTR = COUT + 4;                     // padded px stride (u32)
    constexpr int STAGEB = 2 * (6 * RS) * 2;           // Ah+Al bytes
    constexpr int EPIB = (OUT_MODE == 1) ? (4 * 64 * PSTR * 4) : (COUT * 4 * 66 * 4);
    constexpr int LBYTES = STAGEB > EPIB ? STAGEB : EPIB;
    __shared__ __align__(16) unsigned char LB[LBYTES];
    unsigned short* Ah = (unsigned short*)LB;
    unsigned short* Al = Ah + 6 * RS;

    const int tid = threadIdx.x;
    const int bx = blockIdx.x * 64, by = blockIdx.y * 4;
    const int lane = tid & 63, rw = tid >> 6;

    if constexpr (IN_MODE == 1) {
        constexpr int CPP = CIN / 4;
        constexpr int CROW = 66 * CPP;
        constexpr int TOT = 6 * CROW;
        constexpr int NLOAD = (TOT + 255) / 256;
        const uint32_t* gp = (const uint32_t*)in;

        uint4v regs[NLOAD];
#pragma unroll
        for (int k = 0; k < NLOAD; ++k) {
            int idx = tid + k * 256;
            uint4v v = uint4v{0u, 0u, 0u, 0u};
            if (idx < TOT) {
                int r = idx / CROW;
                int j = idx - r * CROW;
                int gy = by - 1 + r;
                int gx = bx - 1 + j / CPP;
                if ((unsigned)gy < 1024u && (unsigned)gx < 1024u)
                    v = *(const uint4v*)(gp + ((size_t)gy << 10) * CIN +
                                         (size_t)(bx - 1) * CIN + (size_t)j * 4);
            }
            regs[k] = v;
        }
#pragma unroll
        for (int k = 0; k < NLOAD; ++k) {
            int idx = tid + k * 256;
            if (idx < TOT) {
                int r = idx / CROW;
                int j = idx - r * CROW;
                int px = j / CPP, c0 = (j - px * CPP) * 4;
                uint32_t p0 = regs[k].x, p1 = regs[k].y, p2 = regs[k].z, p3 = regs[k].w;
                uint2v hh, ll;
                hh.x = __builtin_amdgcn_perm(p1, p0, 0x05040100u);
                hh.y = __builtin_amdgcn_perm(p3, p2, 0x05040100u);
                ll.x = __builtin_amdgcn_perm(p1, p0, 0x07060302u);
                ll.y = __builtin_amdgcn_perm(p3, p2, 0x07060302u);
                int off = r * RS + px * CIN + c0;
                *(uint2v*)(Ah + off) = hh;
                *(uint2v*)(Al + off) = ll;
            }
        }
    } else {
        constexpr int TOT = 6 * 4 * 66;
        constexpr int NLOAD = (TOT + 255) / 256;  // 7
        const float* xin = (const float*)in;
        float regs[NLOAD];
#pragma unroll
        for (int k = 0; k < NLOAD; ++k) {
            int idx = tid + k * 256;
            float v = 0.f;
            if (idx < TOT) {
                int rc  = idx / 66;
                int px  = idx - rc * 66;
                int r   = rc >> 2, c = rc & 3;
                int gy = by - 1 + r, gx = bx - 1 + px;
                if ((unsigned)gy < 1024u && (unsigned)gx < 1024u)
                    v = xin[(size_t)c * NPIX + ((size_t)gy << 10) + gx];
            }
            regs[k] = v;
        }
#pragma unroll
        for (int k = 0; k < NLOAD; ++k) {
            int idx = tid + k * 256;
            if (idx < TOT) {
                int rc  = idx / 66;
                int px  = idx - rc * 66;
                int r   = rc >> 2, c = rc & 3;
                uint32_t u = __float_as_uint(regs[k]);
                Ah[r * RS + px * CIN + c] = (unsigned short)(u >> 16);
                Al[r * RS + px * CIN + c] =
                    rne_bf16(regs[k] - __uint_as_float(u & 0xFFFF0000u));
            }
        }
    }

    // ---- W fragments -> VGPRs ----
    short8 wh[NF][S], wl[NF][S];
#pragma unroll
    for (int nf = 0; nf < NF; ++nf)
#pragma unroll
        for (int s = 0; s < S; ++s) {
            wh[nf][s] = *(const short8*)(wfH + (size_t)((nf * S + s) * 64 + lane) * 8);
            wl[nf][s] = *(const short8*)(wfL + (size_t)((nf * S + s) * 64 + lane) * 8);
        }

    const int nidx = lane & 15;
    f32x4 acc[4][NF];
#pragma unroll
    for (int nf = 0; nf < NF; ++nf) {
        float bv = (nidx + nf * 16 < COUT) ? bias[nidx + nf * 16] : 0.f;
#pragma unroll
        for (int t = 0; t < 4; ++t) acc[t][nf] = f32x4{bv, bv, bv, bv};
    }

    __syncthreads();

    // ---- K loop ----
    if constexpr (CIN == 32) {
        const int base = rw * RS + (lane & 15) * 32 + (lane >> 4) * 8;
        const unsigned short* pah = Ah + base;
        const unsigned short* pal = Al + base;
#pragma unroll
        for (int s = 0; s < S; ++s) {
            const int ky = s / 3, kx = s - (s / 3) * 3;
#pragma unroll
            for (int t = 0; t < 4; ++t) {
                const int off = ky * RS + kx * 32 + t * 512;
                short8 a = *(const short8*)(pah + off);
                short8 b = *(const short8*)(pal + off);
#pragma unroll
                for (int nf = 0; nf < NF; ++nf) {
                    acc[t][nf] = __builtin_amdgcn_mfma_f32_16x16x32_bf16(a, wh[nf][s], acc[t][nf], 0, 0, 0);
                    acc[t][nf] = __builtin_amdgcn_mfma_f32_16x16x32_bf16(b, wh[nf][s], acc[t][nf], 0, 0, 0);
                    acc[t][nf] = __builtin_amdgcn_mfma_f32_16x16x32_bf16(a, wl[nf][s], acc[t][nf], 0, 0, 0);
                }
            }
        }
    } else if constexpr (CIN == 16) {
        const int g23 = lane >> 5;
        const int base = rw * RS + (lane & 15) * 16 + ((lane >> 4) & 1) * 8;
#pragma unroll
        for (int s = 0; s < S; ++s) {
            const int kk0 = 2 * s, kk1 = 2 * s + 1;
            const int O0 = (kk0 / 3) * RS + (kk0 - (kk0 / 3) * 3) * 16;
            const int O1 = (kk1 <= 8) ? (kk1 / 3) * RS + (kk1 - (kk1 / 3) * 3) * 16 : 0;
            const int offs = base + (g23 ? O1 : O0);
#pragma unroll
            for (int t = 0; t < 4; ++t) {
                short8 a = *(const short8*)(Ah + offs + t * 256);
                short8 b = *(const short8*)(Al + offs + t * 256);
#pragma unroll
                for (int nf = 0; nf < NF; ++nf) {
                    acc[t][nf] = __builtin_amdgcn_mfma_f32_16x16x32_bf16(a, wh[nf][s], acc[t][nf], 0, 0, 0);
                    acc[t][nf] = __builtin_amdgcn_mfma_f32_16x16x32_bf16(b, wh[nf][s], acc[t][nf], 0, 0, 0);
                    acc[t][nf] = __builtin_amdgcn_mfma_f32_16x16x32_bf16(a, wl[nf][s], acc[t][nf], 0, 0, 0);
                }
            }
        }
    } else {  // CIN == 4 (conv1)
        const int base = rw * RS + (lane & 15) * 4;
        const int g2 = (lane >> 4) * 2;
#pragma unroll
        for (int s = 0; s < S; ++s) {
            int kkA = s * 8 + g2, kkB = kkA + 1;
            int kyA = (kkA * 11) >> 5; int kxA = kkA - kyA * 3;
            int poA = (kkA <= 8) ? kyA * RS + kxA * 4 : 0;
            int kyB = (kkB * 11) >> 5; int kxB = kkB - kyB * 3;
            int poB = (kkB <= 8) ? kyB * RS + kxB * 4 : 0;
#pragma unroll
            for (int t = 0; t < 4; ++t) {
                union { short4v q[2]; short8 o; } ua, ub;
                ua.q[0] = *(const short4v*)(Ah + base + poA + t * 64);
                ua.q[1] = *(const short4v*)(Ah + base + poB + t * 64);
                ub.q[0] = *(const short4v*)(Al + base + poA + t * 64);
                ub.q[1] = *(const short4v*)(Al + base + poB + t * 64);
                short8 a = ua.o, b = ub.o;
#pragma unroll
                for (int nf = 0; nf < NF; ++nf) {
                    acc[t][nf] = __builtin_amdgcn_mfma_f32_16x16x32_bf16(a, wh[nf][s], acc[t][nf], 0, 0, 0);
                    acc[t][nf] = __builtin_amdgcn_mfma_f32_16x16x32_bf16(b, wh[nf][s], acc[t][nf], 0, 0, 0);
                    acc[t][nf] = __builtin_amdgcn_mfma_f32_16x16x32_bf16(a, wl[nf][s], acc[t][nf], 0, 0, 0);
                }
            }
        }
    }

    // ---- epilogue ----
    const int mrow = (lane >> 4) * 4;
    if constexpr (OUT_MODE == 0) {
        __syncthreads();
        float* smem = (float*)LB;              // [COUT][4][66]
        if (nidx < COUT) {
#pragma unroll
            for (int t = 0; t < 4; ++t)
#pragma unroll
                for (int j = 0; j < 4; ++j) {
                    float v = acc[t][0][j];
                    if (LEAKY) v = v >= 0.f ? v : 0.2f * v;
                    smem[(nidx * 4 + rw) * 66 + t * 16 + mrow + j] = v;
                }
        }
        __syncthreads();
        float* outp = (float*)out;
#pragma unroll
        for (int k = 0; k < COUT; ++k) {
            int i = tid + k * 256;
            int px = i & 63, r = (i >> 6) & 3, c = i >> 8;
            outp[(size_t)c * NPIX + ((size_t)(by + r) << 10) + bx + px] =
                smem[(c * 4 + r) * 66 + px];
        }
    } else {
        __syncthreads();
        uint32_t* pk = (uint32_t*)LB;          // [4 rows][64 px][PSTR]
#pragma unroll
        for (int t = 0; t < 4; ++t)
#pragma unroll
            for (int nf = 0; nf < NF; ++nf)
#pragma unroll
                for (int j = 0; j < 4; ++j) {
                    float v = acc[t][nf][j];
                    if (LEAKY) v = v >= 0.f ? v : 0.2f * v;
                    int xl = t * 16 + mrow + j;
                    pk[(rw * 64 + xl) * PSTR + nf * 16 + nidx] = pack_hl(v);
                }
        __syncthreads();
        uint32_t* gp = (uint32_t*)out;
        constexpr int ROWU = 64 * COUT;
        constexpr int NU4 = 4 * ROWU / 4;
#pragma unroll
        for (int k = 0; k < (NU4 + 255) / 256; ++k) {
            int i = tid + k * 256;
            if (i < NU4) {
                int e = i * 4;
                int r = e / ROWU;
                int rem = e - r * ROWU;
                int px = rem / COUT, c = rem - px * COUT;
                uint4v val = *(const uint4v*)&pk[(r * 64 + px) * PSTR + c];
                *(uint4v*)(gp + ((size_t)(((by + r) << 10) + bx + px)) * COUT + c) = val;
            }
        }
    }
}

// ---------------- horizontal box sums via row prefix-sum (reflect pad) --------------
template <bool DOB>
__global__ void hbox_kernel(const float* __restrict__ f3,
                            float* __restrict__ hfA, float* __restrict__ hf2A, int pA,
                            float* __restrict__ hfB, float* __restrict__ hf2B, int pB) {
    const int row = blockIdx.x, ch = blockIdx.y, tid = threadIdx.x;
    const float* src = f3 + ch * NPIX + row * W;
    __shared__ float sraw[PROW];
    __shared__ float Pf[PROW + 1], Pf2[PROW + 1];
    __shared__ float wtot[4], wtot2[4];

    for (int i = tid; i < PROW; i += 256)
        sraw[i] = src[reflect1024(i - PADM)];
    __syncthreads();

    float lf[5], lf2[5];
    float sf = 0.f, sf2 = 0.f;
    const int base = tid * 5;
#pragma unroll
    for (int j = 0; j < 5; ++j) {
        int idx = base + j;
        float v = (idx < PROW) ? sraw[idx] : 0.f;
        sf += v;      lf[j] = sf;
        sf2 += v * v; lf2[j] = sf2;
    }
    const int lane = tid & 63, wid = tid >> 6;
    float tf = sf, tf2 = sf2;
#pragma unroll
    for (int off = 1; off < 64; off <<= 1) {
        float a = __shfl_up(tf, off);
        float b = __shfl_up(tf2, off);
        if (lane >= off) { tf += a; tf2 += b; }
    }
    if (lane == 63) { wtot[wid] = tf; wtot2[wid] = tf2; }
    __syncthreads();
    float bse = 0.f, bse2 = 0.f;
    for (int w2 = 0; w2 < wid; ++w2) { bse += wtot[w2]; bse2 += wtot2[w2]; }
    float ex = bse + tf - sf, ex2 = bse2 + tf2 - sf2;
    if (base <= PROW) { Pf[base] = ex; Pf2[base] = ex2; }
#pragma unroll
    for (int j = 0; j < 5; ++j) {
        int idx = base + j + 1;
        if (idx <= PROW) { Pf[idx] = ex + lf[j]; Pf2[idx] = ex2 + lf2[j]; }
    }
    __syncthreads();

    float* dfA  = hfA  + ch * NPIX + row * W;
    float* df2A = hf2A + ch * NPIX + row * W;
    float* dfB  = DOB ? (hfB  + ch * NPIX + row * W) : nullptr;
    float* df2B = DOB ? (hf2B + ch * NPIX + row * W) : nullptr;
    for (int x = tid; x < W; x += 256) {
        int a = x + PADM - pA, b = x + PADM + pA + 1;
        dfA[x]  = Pf[b]  - Pf[a];
        df2A[x] = Pf2[b] - Pf2[a];
        if (DOB) {
            int a2 = x + PADM - pB, b2 = x + PADM + pB + 1;
            dfB[x]  = Pf[b2]  - Pf[a2];
            df2B[x] = Pf2[b2] - Pf2[a2];
        }
    }
}

// ---------------- vertical sliding window + fused 1x1 accumulate ----------------
template <int VRSP, bool DOH>
__global__ __launch_bounds__(512) void vbox_kernel(const float* __restrict__ hf,
                                                   const float* __restrict__ hf2,
                                                   float* __restrict__ fused,
                                                   const float* __restrict__ fw,
                                                   const float* __restrict__ fb,
                                                   uint32_t* __restrict__ h0,
                                                   int kidx, int p, float inv_area) {
    const int tid = threadIdx.x;
    const int colIdx = tid & 63, ch = tid >> 6;
    const int col = blockIdx.x * 64 + colIdx;
    const int r0 = blockIdx.y * VRSP;
    const float* pf  = hf  + ch * NPIX + col;
    const float* pf2 = hf2 + ch * NPIX + col;

    __shared__ float ssq[8][8][65];
    __shared__ uint32_t lh[8][256];
    if (DOH) {
        for (int i = tid; i < 2048; i += 512) ((uint32_t*)lh)[i] = 0u;
    }

    float S1 = 0.f, S2 = 0.f;
    for (int t = -p; t <= p; ++t) {
        int rr = reflect1024(r0 + t);
        S1 += pf[rr * W];
        S2 += pf2[rr * W];
    }

    const float w = fw[kidx];
    const float bias0 = fb[0];
    const int jj = tid >> 6, cc = tid & 63;
    const int sub = jj;

    for (int rb = r0; rb < r0 + VRSP; rb += 8) {
#pragma unroll
        for (int j = 0; j < 8; ++j) {
            int r = rb + j;
            float m1 = S1 * inv_area, m2 = S2 * inv_area;
            float var = fmaxf(m2 - m1 * m1, 1e-6f);
            ssq[ch][j][colIdx] = sqrtf(var);
            int radd = reflect1024(r + 1 + p), rsub = reflect1024(r - p);
            S1 += pf[radd * W] - pf[rsub * W];
            S2 += pf2[radd * W] - pf2[rsub * W];
        }
        __syncthreads();
        float a = 0.f;
#pragma unroll
        for (int c8 = 0; c8 < 8; ++c8) a += ssq[c8][jj][cc];
        float m = powf(a * 0.125f, 0.8f);
        float* fp = fused + ((size_t)(rb + jj) << 10) + blockIdx.x * 64 + cc;
        float outv;
        if (kidx == 0)      { outv = bias0 + w * m; *fp = outv; }
        else if (kidx == 1) { outv = *fp + w * m;   *fp = outv; }
        else                { outv = fmaxf(*fp + w * m, 0.f); *fp = outv; }
        if (DOH) {
            uint32_t u = __float_as_uint(outv);
            uint32_t key = (u & 0x80000000u) ? ~u : (u | 0x80000000u);
            atomicAdd(&lh[sub][key >> 24], 1u);
        }
        __syncthreads();
    }

    if (DOH) {
        __syncthreads();
        if (tid < 256) {
            uint32_t v = 0;
#pragma unroll
            for (int s = 0; s < 8; ++s) v += lh[s][tid];
            if (v) atomicAdd(&h0[tid], v);
        }
    }
}

// ---------------- radix select (8 ranks, 8 bits/pass) ----------------
__global__ void radix_hist_kernel(const float* __restrict__ fused, uint32_t* __restrict__ hist,
                                  const uint32_t* __restrict__ rstate, int pass) {
    __shared__ uint32_t h[8][256];
    int tid = threadIdx.x;
    for (int i = tid; i < 2048; i += 256) ((uint32_t*)h)[i] = 0u;
    __syncthreads();

    uint32_t pref[8];
#pragma unroll
    for (int r = 0; r < 8; ++r) pref[r] = rstate[r];
    uint32_t maskHi = 0xFFFFFFFFu << (32 - 8 * pass);
    int shift = 24 - 8 * pass;

    const uint4v* fp4 = (const uint4v*)fused;
    for (int i = blockIdx.x * blockDim.x + tid; i < NPIX / 4; i += gridDim.x * blockDim.x) {
        uint4v u4 = fp4[i];
#pragma unroll
        for (int e = 0; e < 4; ++e) {
            uint32_t u = (e == 0) ? u4.x : (e == 1) ? u4.y : (e == 2) ? u4.z : u4.w;
            uint32_t key = (u & 0x80000000u) ? ~u : (u | 0x80000000u);
            uint32_t bin = (key >> shift) & 0xFFu;
#pragma unroll
            for (int r = 0; r < 8; ++r) {
                if (((key ^ pref[r]) & maskHi) == 0u)
                    atomicAdd(&h[r][bin], 1u);
            }
        }
    }
    __syncthreads();
    for (int i = tid; i < 2048; i += 256) {
        uint32_t v = ((uint32_t*)h)[i];
        if (v) atomicAdd(&hist[i], v);
    }
}

__device__ __forceinline__ float key_to_float(uint32_t k) {
    uint32_t u = (k & 0x80000000u) ? (k & 0x7FFFFFFFu) : ~k;
    return __uint_as_float(u);
}

__global__ void radix_scan_kernel(uint32_t* __restrict__ hist, uint32_t* __restrict__ rstate,
                                  int pass, const uint32_t* __restrict__ h0,
                                  const double* __restrict__ pstats,
                                  const float* __restrict__ cw, float* __restrict__ scal) {
    int tid = threadIdx.x;
    int shift = 24 - 8 * pass;
    const int lane = tid & 63, wv = tid >> 6;
    __shared__ uint32_t wsum[4];
    __shared__ uint32_t fkey[8];
    for (int r = 0; r < 8; ++r) {
        uint32_t c = (pass == 0) ? h0[tid] : hist[r * 256 + tid];
        uint32_t sc = c;
#pragma unroll
        for (int off = 1; off < 64; off <<= 1) {
            uint32_t t = __shfl_up(sc, off);
            if (lane >= off) sc += t;
        }
        if (lane == 63) wsum[wv] = sc;
        __syncthreads();
        uint32_t base = 0;
        for (int w2 = 0; w2 < wv; ++w2) base += wsum[w2];
        uint32_t incl = base + sc, excl = incl - c;
        uint32_t lr = rstate[8 + r];
        if (lr >= excl && lr < incl) {
            uint32_t nk = rstate[r] | (((uint32_t)tid) << shift);
            rstate[r] = nk;
            rstate[8 + r] = lr - excl;
            if (pass == 3) fkey[r] = nk;
        }
        if (pass > 0) hist[r * 256 + tid] = 0u;
        __syncthreads();
    }

    if (pass == 3) {
        double s1 = pstats[2 * tid], s2 = pstats[2 * tid + 1];
#pragma unroll
        for (int off = 32; off > 0; off >>= 1) {
            s1 += __shfl_down(s1, off);
            s2 += __shfl_down(s2, off);
        }
        __shared__ double gs[4][2];
        if ((tid & 63) == 0) { gs[tid >> 6][0] = s1; gs[tid >> 6][1] = s2; }
        __syncthreads();
        if (tid == 0) {
            float v[8];
#pragma unroll
            for (int r = 0; r < 8; ++r) v[r] = key_to_float(fkey[r]);
            float q25 = v[0] + 0.75f * (v[1] - v[0]);
            float q30 = v[2] + 0.5f * (v[3] - v[2]);
            float q70 = v[4] + 0.5f * (v[5] - v[4]);
            float q75 = v[6] + 0.25f * (v[7] - v[6]);

            const double N = (double)NPIX;
            float gstd[4];
#pragma unroll
            for (int c = 0; c < 4; ++c) {
                double a1 = gs[c][0], a2 = gs[c][1];
                double var = (a2 - a1 * a1 / N) / (N - 1.0);
                gstd[c] = (float)sqrt(var > 0.0 ? var : 0.0);
            }
            float m = fmaxf(fmaxf(cw[0], cw[1]), fmaxf(cw[2], cw[3]));
            float e0 = expf(cw[0] - m), e1 = expf(cw[1] - m);
            float e2 = expf(cw[2] - m), e3 = expf(cw[3] - m);
            float se = e0 + e1 + e2 + e3;
            float cwn[4] = {e0 / se, e1 / se, e2 / se, e3 / se};

            float iqr75 = q75 - q25;
            float low0 = q25 - 0.5f * iqr75;
            float up0  = q75 + 0.5f * iqr75;
            float lsum = 0.f, usum = 0.f;
#pragma unroll
            for (int c = 0; c < 4; ++c) {
                float gf = fminf(fmaxf(gstd[c] * 5.f, 0.5f), 2.f);
                float cs = cwn[c] * gstd[c];
                float cf = fminf(fmaxf(cs * 2.f, 0.8f), 1.2f);
                lsum += low0 * gf * cf;
                usum += up0 * gf * cf;
            }
            float lmean = 0.25f * lsum, umean = 0.25f * usum;
            float l_t = 0.5f * lmean + 0.5f * q30;
            float u_t = 0.5f * umean + 0.5f * q70;
            float iqr = q70 - q30;
            if (iqr < 0.01f) { l_t -= iqr; u_t += iqr; }
            float diff = u_t - l_t;
            float mid0 = 0.5f * (l_t + u_t);
            if (diff < 0.02f) { l_t = mid0 - 0.01f; u_t = mid0 + 0.01f; }
            scal[0] = 0.5f * (l_t + u_t);
            scal[1] = u_t - l_t;
        }
    }
}

// ---------------- sigmoid mean (no store, float4) ----------------
__global__ void sigmoid_kernel(const float* __restrict__ fused, const float* __restrict__ scal,
                               double* __restrict__ nmsum) {
    float mid = scal[0], sc = scal[1];
    float inv = 4.0f / sc;
    float local = 0.f;
    const f32x4* fp4 = (const f32x4*)fused;
    for (int i = blockIdx.x * blockDim.x + threadIdx.x; i < NPIX / 4; i += gridDim.x * blockDim.x) {
        f32x4 v = fp4[i];
#pragma unroll
        for (int e = 0; e < 4; ++e) {
            float t = (v[e] - mid) * inv;
            local += 1.0f / (1.0f + expf(-t));
        }
    }
    __shared__ float red[256];
    red[threadIdx.x] = local;
    __syncthreads();
    for (int off = 128; off > 0; off >>= 1) {
        if (threadIdx.x < off) red[threadIdx.x] += red[threadIdx.x + off];
        __syncthreads();
    }
    if (threadIdx.x == 0) atomicAdd(nmsum, (double)red[0]);
}

// ---------------- final mask (recompute sigmoid; float4) ----------------
__global__ void final_kernel(const float* __restrict__ fused, const float* __restrict__ scal,
                             const double* __restrict__ nmsum, float* __restrict__ out) {
    float nm = (float)(nmsum[0] / (double)NPIX);
    float a, b;
    if (nm > 0.65f)      { a = 0.10f; b = 0.50f; }
    else if (nm < 0.35f) { a = 0.20f; b = 0.50f; }
    else                 { a = 0.15f; b = 0.55f; }
    float mid = scal[0], inv = 4.0f / scal[1];
    const f32x4* fp4 = (const f32x4*)fused;
    f32x4* op4 = (f32x4*)out;
    for (int i = blockIdx.x * blockDim.x + threadIdx.x; i < NPIX / 4; i += gridDim.x * blockDim.x) {
        f32x4 v = fp4[i];
        f32x4 r;
#pragma unroll
        for (int e = 0; e < 4; ++e) {
            float t = (v[e] - mid) * inv;
            float n = 1.0f / (1.0f + expf(-t));
            r[e] = a + b * n;
        }
        op4[i] = r;
    }
}

// ---------------- launch ----------------
extern "C" void kernel_launch(void* const* d_in, const int* in_sizes, int n_in,
                              void* d_out, int out_size, void* d_ws, size_t ws_size,
                              hipStream_t stream) {
    const float* x   = (const float*)d_in[0];
    const float* w1  = (const float*)d_in[1];
    const float* b1  = (const float*)d_in[2];
    const float* w2  = (const float*)d_in[3];
    const float* b2  = (const float*)d_in[4];
    const float* w3  = (const float*)d_in[5];
    const float* b3  = (const float*)d_in[6];
    const float* cw  = (const float*)d_in[7];
    const float* fw  = (const float*)d_in[8];
    const float* fb  = (const float*)d_in[9];

    char* ws = (char*)d_ws;
    uint32_t* f1p = (uint32_t*)(ws + OFF_F1P);
    uint32_t* f2p = (uint32_t*)(ws + OFF_F2P);
    float* f3    = (float*)(ws + OFF_F3);     // NCHW 8c fp32
    float* hf    = (float*)(ws + OFF_HF);     // scale-A pair
    float* hf2   = (float*)(ws + OFF_HF2);
    float* hf25  = (float*)(ws + OFF_HF25);   // scale-B pair (over dead f2p)
    float* hf225 = (float*)(ws + OFF_HF225);
    float* fused = (float*)(ws + OFF_FUSED);
    double* pstats = (double*)(ws + OFF_PSTAT);
    double* nmsum  = (double*)(ws + OFF_NMSUM);
    uint32_t* hist   = (uint32_t*)(ws + OFF_HIST);
    uint32_t* rstate = (uint32_t*)(ws + OFF_RSTATE);
    float* scal = (float*)(ws + OFF_SCAL);
    uint32_t* h0 = (uint32_t*)(ws + OFF_H0);
    unsigned short* wf1H = (unsigned short*)(ws + OFF_WT);            // 2048 elems
    unsigned short* wf1L = wf1H + 2048;
    unsigned short* wf2H = wf1L + 2048;                               // 4608 elems
    unsigned short* wf2L = wf2H + 4608;
    unsigned short* wf3H = wf2L + 4608;                               // 2560 elems
    unsigned short* wf3L = wf3H + 2560;

    // prep: init + weight frags + x-stats partials (293 blocks)
    prep_kernel<<<293, 256, 0, stream>>>(w1, w2, w3, wf1H, wf1L, wf2H, wf2L, wf3H, wf3L,
                                         x, pstats, nmsum, hist, rstate, h0);

    // feature extractor: MFMA implicit-GEMM convs (bf16x3), packed u32 intermediates
    dim3 cgrid(16, 256);
    mconv_kernel<4, 32, 2, true, 1, 0, 4><<<cgrid, 256, 0, stream>>>(
        x, wf1H, wf1L, b1, f1p);
    mconv_kernel<32, 16, 9, true, 1, 1, 3><<<cgrid, 256, 0, stream>>>(
        f1p, wf2H, wf2L, b2, f2p);
    mconv_kernel<16, 8, 5, false, 0, 1, 4><<<cgrid, 256, 0, stream>>>(
        f2p, wf3H, wf3L, b3, f3);

    // multi-scale std maps + fused 1x1 accumulate (k order 0,1,2 via stream order)
    hbox_kernel<true><<<dim3(H, 8), 256, 0, stream>>>(f3, hf, hf2, 5, hf25, hf225, 12);
    vbox_kernel<32, false><<<dim3(16, 32), 512, 0, stream>>>(hf, hf2, fused, fw, fb,
                                                             nullptr, 0, 5, 1.0f / 121.0f);
    hbox_kernel<false><<<dim3(H, 8), 256, 0, stream>>>(f3, hf, hf2, 24,
                                                       nullptr, nullptr, 0);
    vbox_kernel<32, false><<<dim3(16, 32), 512, 0, stream>>>(hf25, hf225, fused, fw, fb,
                                                             nullptr, 1, 12, 1.0f / 625.0f);
    // last scale also builds the pass-0 radix histogram from final fused values
    vbox_kernel<64, true><<<dim3(16, 16), 512, 0, stream>>>(hf, hf2, fused, fw, fb,
                                                            h0, 2, 24, 1.0f / 2401.0f);

    // exact quantiles: pass 0 histogram came from vbox; 3 more hist+scan passes
    radix_scan_kernel<<<1, 256, 0, stream>>>(hist, rstate, 0, h0, pstats, cw, scal);
    for (int pass = 1; pass < 4; ++pass) {
        radix_hist_kernel<<<1024, 256, 0, stream>>>(fused, hist, rstate, pass);
        radix_scan_kernel<<<1, 256, 0, stream>>>(hist, rstate, pass, h0, pstats, cw, scal);
    }

    sigmoid_kernel<<<1024, 256, 0, stream>>>(fused, scal, nmsum);
    final_kernel<<<1024, 256, 0, stream>>>(fused, scal, nmsum, (float*)d_out);
}